// Round 1
// baseline (117.390 us; speedup 1.0000x reference)
//
#include <hip/hip_runtime.h>

// Problem constants (from reference)
#define BB 2
#define NN 32768
#define SS 1024
#define CSRC 35
#define KK 32
#define R2 1.0f
#define COUT 39   // 3 (xyz-kp) + 1 (intensity) + 35 (source)

// One wave (64 lanes) per keypoint; 4 waves (256 threads) per block.
__global__ __launch_bounds__(256) void dfe_kernel(
    const float* __restrict__ src,    // B*N*35
    const float* __restrict__ inten,  // B*N
    const float* __restrict__ kpt,    // B*S*4
    float* __restrict__ out)          // B*S*K*39
{
    const int lane  = threadIdx.x & 63;
    const int w     = threadIdx.x >> 6;
    const int kp_id = blockIdx.x * 4 + w;          // 0 .. B*S-1
    const int b     = kp_id >> 10;                 // S = 1024
    // s = kp_id & 1023 (implicit in kp_id addressing)

    __shared__ int sidx[4][KK];

    const float* kp = kpt + (size_t)kp_id * 4;
    const float kx = kp[0], ky = kp[1], kz = kp[2];
    // kq = (kx*kx + ky*ky) + kz*kz  -- exact reference association, no FMA
    const float kq = __fadd_rn(__fadd_rn(__fmul_rn(kx, kx), __fmul_rn(ky, ky)),
                               __fmul_rn(kz, kz));

    const float* sb = src + (size_t)b * NN * CSRC;
    const float* ib = inten + (size_t)b * NN;

    // ---- Phase A: ordered scan, collect first 32 in-radius indices ----
    int count = 0;
    for (int base = 0; base < NN && count < KK; base += 256) {
        bool in[4];
        // 4 independent distance evaluations -> ILP hides load latency
        #pragma unroll
        for (int c = 0; c < 4; ++c) {
            const int i = base + c * 64 + lane;
            const float* p = sb + (size_t)i * CSRC;
            const float x = p[0], y = p[1], z = p[2];
            const float xq  = __fadd_rn(__fadd_rn(__fmul_rn(x, x), __fmul_rn(y, y)),
                                        __fmul_rn(z, z));
            const float dot = __fadd_rn(__fadd_rn(__fmul_rn(kx, x), __fmul_rn(ky, y)),
                                        __fmul_rn(kz, z));
            // sq = (kq + xq) - 2.0*dot  -- exact reference association
            const float sq = __fsub_rn(__fadd_rn(kq, xq), __fmul_rn(2.0f, dot));
            in[c] = !(sq > R2);   // in-radius iff NOT (sq > r^2), matches jnp.where
        }
        // ordered compaction per 64-wide sub-chunk
        #pragma unroll
        for (int c = 0; c < 4; ++c) {
            const unsigned long long m = __ballot(in[c]);
            const int pre = __popcll(m & ((1ull << lane) - 1ull));
            if (in[c]) {
                const int slot = count + pre;
                if (slot < KK) sidx[w][slot] = base + c * 64 + lane;
            }
            count += __popcll(m);
        }
    }

    // ---- Pad unused slots with the first index (count >= 1 guaranteed:
    //      keypoint s equals source row s exactly -> sq == 0) ----
    const int cnt = count < KK ? count : KK;
    const int first = sidx[w][0];
    if (lane >= cnt && lane < KK) sidx[w][lane] = first;

    // ---- Phase B: gather + write 32*39 = 1248 floats, 64 lanes ----
    float* ob = out + (size_t)kp_id * (KK * COUT);
    for (int t = lane; t < KK * COUT; t += 64) {
        const int k = t / COUT;
        const int j = t - k * COUT;
        const int i = sidx[w][k];
        float v;
        if (j < 3) {
            const float kc = (j == 0) ? kx : ((j == 1) ? ky : kz);
            v = __fsub_rn(sb[(size_t)i * CSRC + j], kc);
        } else if (j == 3) {
            v = ib[i];
        } else {
            v = sb[(size_t)i * CSRC + (j - 4)];
        }
        ob[t] = v;
    }
}

extern "C" void kernel_launch(void* const* d_in, const int* in_sizes, int n_in,
                              void* d_out, int out_size, void* d_ws, size_t ws_size,
                              hipStream_t stream) {
    const float* src   = (const float*)d_in[0];  // (B, N, 35)
    const float* inten = (const float*)d_in[1];  // (B, N, 1)
    const float* kpt   = (const float*)d_in[2];  // (B, S, 4)
    float* out = (float*)d_out;                  // (B, S, K, 39)

    const int n_kp = BB * SS;                    // 2048 keypoints
    dim3 grid(n_kp / 4);                         // 4 keypoints per 256-thread block
    dim3 block(256);
    dfe_kernel<<<grid, block, 0, stream>>>(src, inten, kpt, out);
}

// Round 2
// 45.041 us; speedup vs baseline: 2.6063x; 2.6063x over previous
//
#include <hip/hip_runtime.h>

// Problem constants (from reference)
#define BB 2
#define NN 32768
#define SS 1024
#define CSRC 35
#define KK 32
#define R2 1.0f
#define COUT 39   // 3 (xyz-kp) + 1 (intensity) + 35 (source)

// ---- Pre-pass: pack {x, y, z, (x*x+y*y)+z*z} per point, coalesced ----
__global__ __launch_bounds__(256) void pack_kernel(
    const float* __restrict__ src,   // B*N*35
    float4* __restrict__ pk)         // B*N
{
    const int i = blockIdx.x * 256 + threadIdx.x;   // 0 .. B*N-1
    if (i >= BB * NN) return;
    const float* p = src + (size_t)i * CSRC;
    const float x = p[0], y = p[1], z = p[2];
    // EXACT same association as reference xq: (x*x + y*y) + z*z, no FMA
    const float xq = __fadd_rn(__fadd_rn(__fmul_rn(x, x), __fmul_rn(y, y)),
                               __fmul_rn(z, z));
    pk[i] = make_float4(x, y, z, xq);
}

// ---- Main: one 256-thread block (4 waves) per keypoint ----
__global__ __launch_bounds__(256) void dfe_kernel(
    const float* __restrict__ src,    // B*N*35
    const float* __restrict__ inten,  // B*N
    const float* __restrict__ kpt,    // B*S*4
    const float4* __restrict__ pk,    // B*N packed {x,y,z,xq}
    float* __restrict__ out)          // B*S*K*39
{
    const int tid  = threadIdx.x;          // 0..255
    const int lane = tid & 63;
    const int w    = tid >> 6;             // wave 0..3
    const int kp_id = blockIdx.x;          // 0 .. B*S-1
    const int b     = kp_id >> 10;         // S = 1024

    __shared__ int cnt[4][4];              // [chunk][wave] hit counts
    __shared__ int sidx[KK];

    const float* kp = kpt + (size_t)kp_id * 4;
    const float kx = kp[0], ky = kp[1], kz = kp[2];
    const float kq = __fadd_rn(__fadd_rn(__fmul_rn(kx, kx), __fmul_rn(ky, ky)),
                               __fmul_rn(kz, kz));

    const float*  sb = src   + (size_t)b * NN * CSRC;
    const float*  ib = inten + (size_t)b * NN;
    const float4* pb = pk    + (size_t)b * NN;

    // ---- Phase A: ordered scan, 1024 points / iteration across the block ----
    int count = 0;
    for (int base = 0; base < NN; base += 1024) {
        if (count >= KK) break;
        bool in[4];
        #pragma unroll
        for (int c = 0; c < 4; ++c) {
            const int i = base + c * 256 + tid;
            const float4 p = pb[i];
            const float dot = __fadd_rn(__fadd_rn(__fmul_rn(kx, p.x), __fmul_rn(ky, p.y)),
                                        __fmul_rn(kz, p.z));
            // sq = (kq + xq) - 2.0*dot  -- exact reference association
            const float sq = __fsub_rn(__fadd_rn(kq, p.w), __fmul_rn(2.0f, dot));
            in[c] = !(sq > R2);
        }
        unsigned long long m[4];
        #pragma unroll
        for (int c = 0; c < 4; ++c) {
            m[c] = __ballot(in[c]);
            if (lane == 0) cnt[c][w] = __popcll(m[c]);
        }
        __syncthreads();
        // ordered slot = count + (all hits in earlier chunks) +
        //                (earlier waves, same chunk) + (earlier lanes, same wave)
        int chunk_base = count;
        #pragma unroll
        for (int c = 0; c < 4; ++c) {
            if (in[c]) {
                int off = chunk_base;
                for (int w2 = 0; w2 < w; ++w2) off += cnt[c][w2];
                off += __popcll(m[c] & ((1ull << lane) - 1ull));
                if (off < KK) sidx[off] = base + c * 256 + tid;
            }
            chunk_base += cnt[c][0] + cnt[c][1] + cnt[c][2] + cnt[c][3];
        }
        count = chunk_base;
        __syncthreads();   // sidx/cnt settled before next iteration overwrites
    }

    // ---- Pad with first index (count >= 1: keypoint s == source row s) ----
    const int cclamp = count < KK ? count : KK;
    const int first = sidx[0];
    if (tid >= cclamp && tid < KK) sidx[tid] = first;
    __syncthreads();

    // ---- Phase B: gather + write 32*39 = 1248 floats with 256 threads ----
    float* ob = out + (size_t)kp_id * (KK * COUT);
    for (int t = tid; t < KK * COUT; t += 256) {
        const int k = t / COUT;
        const int j = t - k * COUT;
        const int i = sidx[k];
        float v;
        if (j < 3) {
            const float kc = (j == 0) ? kx : ((j == 1) ? ky : kz);
            v = __fsub_rn(sb[(size_t)i * CSRC + j], kc);
        } else if (j == 3) {
            v = ib[i];
        } else {
            v = sb[(size_t)i * CSRC + (j - 4)];
        }
        ob[t] = v;
    }
}

extern "C" void kernel_launch(void* const* d_in, const int* in_sizes, int n_in,
                              void* d_out, int out_size, void* d_ws, size_t ws_size,
                              hipStream_t stream) {
    const float* src   = (const float*)d_in[0];  // (B, N, 35)
    const float* inten = (const float*)d_in[1];  // (B, N, 1)
    const float* kpt   = (const float*)d_in[2];  // (B, S, 4)
    float* out = (float*)d_out;                  // (B, S, K, 39)
    float4* pk = (float4*)d_ws;                  // B*N*16 B = 1 MiB

    pack_kernel<<<(BB * NN + 255) / 256, 256, 0, stream>>>(src, pk);
    dfe_kernel<<<BB * SS, 256, 0, stream>>>(src, inten, kpt, pk, out);
}